// Round 13
// baseline (74.565 us; speedup 1.0000x reference)
//
#include <hip/hip_runtime.h>

typedef __attribute__((ext_vector_type(8))) short short8;
typedef __attribute__((ext_vector_type(4))) float f32x4;
typedef __attribute__((ext_vector_type(4))) int   i32x4;

#define IN_F   4096
#define OUT_F  16384
#define NG     32
#define NCH    32           // 64-int chunks per wave K-half (2048/64)

// f32 -> bf16 round-to-nearest-even
static __device__ __forceinline__ short f2bf(float f) {
    union { float f; unsigned u; } c; c.f = f;
    unsigned u = c.u;
    u += 0x7FFF + ((u >> 16) & 1);
    return (short)(u >> 16);
}

// int8-range -> bf16 (exact for |v| <= 127)
static __device__ __forceinline__ short i2bf(int v) {
    union { float f; unsigned u; } c; c.f = (float)v;
    return (short)(c.u >> 16);
}

// Single fused kernel: ZERO mid-loop barriers, no prepass, no workspace.
// 512 thr = 8 fully-independent waves. Wave (grp, wk): 16 out-cols x K-half;
// computes both m-halves. Private LDS region per wave (4 slots x 4 KB),
// per-wave counted vmcnt pipeline (depth 3). x read directly as f32 (L2-hot)
// and converted to bf16 in-register (R2-proven path, same rounding).
// Grid 256 = 1 block/CU, 8 free-running waves/CU, LDS 128 KB.
__global__ __launch_bounds__(512, 2)
void qlin_kernel(const float* __restrict__ x,       // [32][4096] f32
                 const int*   __restrict__ qw,      // [16384][4096] int32
                 const float* __restrict__ scales,  // [16384][32] f32
                 const float* __restrict__ bias,    // [16384] f32
                 float*       __restrict__ out)     // [32][16384] f32
{
    __shared__ int lqw[8][4][16][64];   // [wave][slot][row][int] = 128 KB

    const int tid  = threadIdx.x;
    const int wv   = tid >> 6;
    const int lane = tid & 63;
    const int l15  = lane & 15;
    const int l4   = lane >> 4;
    const int grp  = wv >> 1;          // col-group 0..3
    const int wk   = wv & 1;           // K-half
    const int col0 = blockIdx.x * 64 + grp * 16;
    const int swz  = (l15 & 7) << 4;

    // --- preloads (oldest VMEM; retired by the prologue wait) ---
    const float* scr = scales + (size_t)(col0 + l15) * NG + wk * 16;
    f32x4 sc4[4];
#pragma unroll
    for (int j = 0; j < 4; ++j) sc4[j] = *(const f32x4*)(scr + 4 * j);
    const float bv = bias[col0 + l15];
    asm volatile("" ::: "memory");     // pin: preloads before stage(0)

    // --- stage chunk c (64 ints) of this wave's 16 rows into slot sl ---
    // 4 instrs, each 1 KB = 4 rows x 256 B, LDS linear; global source
    // pre-swizzled by ((row&7)<<4) (read applies same XOR; rule #21).
    auto STAGE = [&](int c, int sl) {
#pragma unroll
        for (int i = 0; i < 4; ++i) {
            const int row = 4 * i + (lane >> 4);
            const int byt = ((lane & 15) * 16) ^ ((row & 7) << 4);
            const char* src = (const char*)(qw + (size_t)(col0 + row) * IN_F
                                            + wk * 2048 + c * 64) + byt;
            __builtin_amdgcn_global_load_lds(
                (const __attribute__((address_space(1))) unsigned int*)src,
                (__attribute__((address_space(3))) unsigned int*)&lqw[wv][sl][4 * i][0],
                16, 0, 0);
        }
    };

    // --- x fragments: direct f32 loads (L2-hot), parked, parity-2 ---
    // lane (l15,l4) of k-tile t, m-half h reads x[16h+l15][t*32+l4*8 .. +8]
    const float* xr0 = x + (size_t)l15 * IN_F + l4 * 8;          // h=0
    const float* xr1 = x + (size_t)(16 + l15) * IN_F + l4 * 8;   // h=1
    f32x4 xf[2][2][2][2];              // [parity][s][h][pair]  (64 VGPR)
    auto XLOAD = [&](int c, int par) {
        const int t0 = wk * 64 + c * 2;
#pragma unroll
        for (int s = 0; s < 2; ++s) {
            const int kc = (t0 + s) * 32;
            xf[par][s][0][0] = *(const f32x4*)(xr0 + kc);
            xf[par][s][0][1] = *(const f32x4*)(xr0 + kc + 4);
            xf[par][s][1][0] = *(const f32x4*)(xr1 + kc);
            xf[par][s][1][1] = *(const f32x4*)(xr1 + kc + 4);
        }
    };

    f32x4 acc[2] = {{0.f, 0.f, 0.f, 0.f}, {0.f, 0.f, 0.f, 0.f}};

    // --- compute chunk c from slot sl (all indices static) ---
    auto COMPUTE = [&](int c, int sl, int par, float sc) {
        const char* lrow = (const char*)&lqw[wv][sl][l15][0];
        // convert parked f32 x-fragments to bf16 (RNE)
        short8 a[2][2];
#pragma unroll
        for (int s = 0; s < 2; ++s)
#pragma unroll
            for (int h = 0; h < 2; ++h)
#pragma unroll
                for (int j = 0; j < 4; ++j) {
                    a[s][h][j]     = f2bf(xf[par][s][h][0][j]);
                    a[s][h][j + 4] = f2bf(xf[par][s][h][1][j]);
                }
        f32x4 ag[2] = {{0.f, 0.f, 0.f, 0.f}, {0.f, 0.f, 0.f, 0.f}};
#pragma unroll
        for (int s = 0; s < 2; ++s) {
            const int off = (s * 128 + l4 * 32) ^ swz;
            i32x4 q0 = *(const i32x4*)(lrow + off);
            i32x4 q1 = *(const i32x4*)(lrow + (off ^ 16));
            short8 bfr;
#pragma unroll
            for (int j = 0; j < 4; ++j) { bfr[j] = i2bf(q0[j]); bfr[j + 4] = i2bf(q1[j]); }
            ag[0] = __builtin_amdgcn_mfma_f32_16x16x32_bf16(a[s][0], bfr, ag[0], 0, 0, 0);
            ag[1] = __builtin_amdgcn_mfma_f32_16x16x32_bf16(a[s][1], bfr, ag[1], 0, 0, 0);
        }
#pragma unroll
        for (int h = 0; h < 2; ++h)
#pragma unroll
            for (int r = 0; r < 4; ++r) acc[h][r] += sc * ag[h][r];
    };

    // --- prologue: st0,x0,st1,x1,st2 (28 VMEM after preloads);
    //     vmcnt(16) retires preloads(5) + st0(4) + x0(8) ---
    STAGE(0, 0);
    asm volatile("" ::: "memory");
    XLOAD(0, 0);
    asm volatile("" ::: "memory");
    STAGE(1, 1);
    asm volatile("" ::: "memory");
    XLOAD(1, 1);
    asm volatile("" ::: "memory");
    STAGE(2, 2);
    asm volatile("s_waitcnt vmcnt(16)" ::: "memory");
    __builtin_amdgcn_sched_barrier(0);

    // --- steady (NO barriers): compute(i) || {x(i+2), stage(i+3)}
    // At iter-i wait: outstanding st(i+1)4 x(i+1)8 st(i+2)4 x(i+2)8 st(i+3)4
    // = 28; vmcnt(16) retires st(i+1)+x(i+1) -> next iter's inputs ready.
#pragma unroll
    for (int i = 0; i <= 28; ++i) {
        COMPUTE(i, i & 3, i & 1, sc4[i >> 3][(i >> 1) & 3]);
        XLOAD(i + 2, i & 1);
        asm volatile("" ::: "memory");
        STAGE(i + 3, (i + 3) & 3);
        asm volatile("s_waitcnt vmcnt(16)" ::: "memory");
        __builtin_amdgcn_sched_barrier(0);
    }
    // tail: i=29 -> need st(30)+x(30) retired; keep {st31, x31} in flight
    COMPUTE(29, 1, 1, sc4[3][2]);
    XLOAD(31, 1);
    asm volatile("s_waitcnt vmcnt(12)" ::: "memory");
    __builtin_amdgcn_sched_barrier(0);
    COMPUTE(30, 2, 0, sc4[3][3]);
    asm volatile("s_waitcnt vmcnt(0)" ::: "memory");
    __builtin_amdgcn_sched_barrier(0);
    COMPUTE(31, 3, 1, sc4[3][3]);

    // --- epilogue: single block-wide sync, pairwise wk-reduce, store ---
    __syncthreads();
    float* red = (float*)&lqw[0][0][0][0];    // [8][64][2][4] = 16 KB alias
#pragma unroll
    for (int h = 0; h < 2; ++h)
        *(f32x4*)&red[(size_t)(((wv * 64 + lane) * 2) + h) * 4] = acc[h];
    __syncthreads();
    if (wk == 0) {                             // even waves store
#pragma unroll
        for (int h = 0; h < 2; ++h) {
            f32x4 hi = *(const f32x4*)&red[(size_t)((((wv + 1) * 64 + lane) * 2) + h) * 4];
#pragma unroll
            for (int r = 0; r < 4; ++r)
                out[(size_t)(h * 16 + l4 * 4 + r) * OUT_F + col0 + l15] =
                    acc[h][r] + hi[r] + bv;
        }
    }
}

extern "C" void kernel_launch(void* const* d_in, const int* in_sizes, int n_in,
                              void* d_out, int out_size, void* d_ws, size_t ws_size,
                              hipStream_t stream) {
    const float* x      = (const float*)d_in[0];
    const int*   qw     = (const int*)d_in[1];
    const float* scales = (const float*)d_in[2];
    const float* bias   = (const float*)d_in[3];
    float*       out    = (float*)d_out;

    hipLaunchKernelGGL(qlin_kernel, dim3(OUT_F / 64), dim3(512), 0, stream,
                       x, qw, scales, bias, out);
}

// Round 14
// 52.133 us; speedup vs baseline: 1.4303x; 1.4303x over previous
//
#include <hip/hip_runtime.h>

typedef __attribute__((ext_vector_type(8))) short short8;
typedef __attribute__((ext_vector_type(4))) float f32x4;
typedef __attribute__((ext_vector_type(4))) int   i32x4;

#define IN_F   4096
#define OUT_F  16384
#define NG     32
#define NCH    32           // 64-int chunks per wave K-half (2048/64)

// f32 -> bf16 round-to-nearest-even
static __device__ __forceinline__ short f2bf(float f) {
    union { float f; unsigned u; } c; c.f = f;
    unsigned u = c.u;
    u += 0x7FFF + ((u >> 16) & 1);
    return (short)(u >> 16);
}

// int8-range -> bf16 (exact for |v| <= 127)
static __device__ __forceinline__ short i2bf(int v) {
    union { float f; unsigned u; } c; c.f = (float)v;
    return (short)(c.u >> 16);
}

// Pre-pass: x[32][4096] f32 -> xT bf16 in MFMA-A-fragment order.
// xT layout: [t][h][ln][8] bf16, t = k/32, h = m-half, ln = l15*4 + l4.
// Load-bearing for coalescing (R13 ablation: inline scatter costs ~23 us).
__global__ __launch_bounds__(256)
void xconv_kernel(const float* __restrict__ x, unsigned short* __restrict__ xT) {
    const int g   = blockIdx.x * 256 + threadIdx.x;   // 16384 threads
    const int t   = g >> 7;
    const int rem = g & 127;
    const int h   = rem >> 6;
    const int ln  = rem & 63;
    const int l15 = ln >> 2;
    const int l4  = ln & 3;
    const float* src = x + (size_t)(16 * h + l15) * IN_F + t * 32 + l4 * 8;
    f32x4 a = *(const f32x4*)src;
    f32x4 b = *(const f32x4*)(src + 4);
    short8 o;
#pragma unroll
    for (int j = 0; j < 4; ++j) { o[j] = f2bf(a[j]); o[j + 4] = f2bf(b[j]); }
    *(short8*)(xT + (size_t)g * 8) = o;
}

// Main: ZERO mid-loop barriers. 512 thr = 8 fully-independent waves.
// Wave (grp, wk): 16 out-cols (grp) x K-half (wk); computes BOTH m-halves.
// Each wave stages its own 16 qw rows into its private LDS region
// (4 slots x 4 KB) and reads only its own data -> per-wave vmcnt(12)
// pipeline (depth 3), no s_barrier until the final reduce.
// Grid 256 = 1 block/CU, 8 free-running waves/CU, LDS 128 KB.
__global__ __launch_bounds__(512, 2)
void qlin_kernel(const unsigned short* __restrict__ xT,
                 const int*   __restrict__ qw,
                 const float* __restrict__ scales,
                 const float* __restrict__ bias,
                 float*       __restrict__ out)
{
    __shared__ int lqw[8][4][16][64];   // [wave][slot][row][int] = 128 KB

    const int tid  = threadIdx.x;
    const int wv   = tid >> 6;
    const int lane = tid & 63;
    const int l15  = lane & 15;
    const int l4   = lane >> 4;
    const int grp  = wv >> 1;          // col-group 0..3
    const int wk   = wv & 1;           // K-half
    const int col0 = blockIdx.x * 64 + grp * 16;
    const int swz  = (l15 & 7) << 4;

    // --- preloads (oldest VMEM; retired by the prologue wait) ---
    const float* scr = scales + (size_t)(col0 + l15) * NG + wk * 16;
    f32x4 sc4[4];
#pragma unroll
    for (int j = 0; j < 4; ++j) sc4[j] = *(const f32x4*)(scr + 4 * j);
    const float bv = bias[col0 + l15];
    asm volatile("" ::: "memory");     // pin: preloads before stage(0)

    // --- stage chunk c (64 ints) of this wave's 16 rows into slot sl ---
    // 4 instrs, each 1 KB = 4 rows x 256 B, LDS linear; global source
    // pre-swizzled by ((row&7)<<4) (read applies same XOR; rule #21).
    auto STAGE = [&](int c, int sl) {
#pragma unroll
        for (int i = 0; i < 4; ++i) {
            const int row = 4 * i + (lane >> 4);
            const int byt = ((lane & 15) * 16) ^ ((row & 7) << 4);
            const char* src = (const char*)(qw + (size_t)(col0 + row) * IN_F
                                            + wk * 2048 + c * 64) + byt;
            __builtin_amdgcn_global_load_lds(
                (const __attribute__((address_space(1))) unsigned int*)src,
                (__attribute__((address_space(3))) unsigned int*)&lqw[wv][sl][4 * i][0],
                16, 0, 0);
        }
    };

    // --- x fragments: 2 k-tiles x 2 m-halves per chunk, parity-2 park ---
    const unsigned short* xg = xT + (size_t)(l15 * 4 + l4) * 8;
    short8 xa[2][2][2];                // [parity][s][h]
    auto XLOAD = [&](int c, int par) {
        const int t0 = wk * 64 + c * 2;
#pragma unroll
        for (int s = 0; s < 2; ++s)
#pragma unroll
            for (int h = 0; h < 2; ++h)
                xa[par][s][h] = *(const short8*)(xg + (size_t)((t0 + s) * 2 + h) * 512);
    };

    f32x4 acc[2] = {{0.f, 0.f, 0.f, 0.f}, {0.f, 0.f, 0.f, 0.f}};

    // --- compute chunk c from slot sl (all indices static) ---
    auto COMPUTE = [&](int c, int sl, int par, float sc) {
        const char* lrow = (const char*)&lqw[wv][sl][l15][0];
        f32x4 ag[2] = {{0.f, 0.f, 0.f, 0.f}, {0.f, 0.f, 0.f, 0.f}};
#pragma unroll
        for (int s = 0; s < 2; ++s) {
            const int off = (s * 128 + l4 * 32) ^ swz;
            i32x4 q0 = *(const i32x4*)(lrow + off);
            i32x4 q1 = *(const i32x4*)(lrow + (off ^ 16));
            short8 bfr;
#pragma unroll
            for (int j = 0; j < 4; ++j) { bfr[j] = i2bf(q0[j]); bfr[j + 4] = i2bf(q1[j]); }
            ag[0] = __builtin_amdgcn_mfma_f32_16x16x32_bf16(xa[par][s][0], bfr, ag[0], 0, 0, 0);
            ag[1] = __builtin_amdgcn_mfma_f32_16x16x32_bf16(xa[par][s][1], bfr, ag[1], 0, 0, 0);
        }
#pragma unroll
        for (int h = 0; h < 2; ++h)
#pragma unroll
            for (int r = 0; r < 4; ++r) acc[h][r] += sc * ag[h][r];
    };

    // --- prologue: st0,x0,st1,x1,st2 (20 issued); vmcnt(12) retires st0+x0 ---
    STAGE(0, 0);
    asm volatile("" ::: "memory");
    XLOAD(0, 0);
    asm volatile("" ::: "memory");
    STAGE(1, 1);
    asm volatile("" ::: "memory");
    XLOAD(1, 1);
    asm volatile("" ::: "memory");
    STAGE(2, 2);
    asm volatile("s_waitcnt vmcnt(12)" ::: "memory");
    __builtin_amdgcn_sched_barrier(0);

    // --- steady (NO barriers): compute(i) || {x(i+2), stage(i+3)}; vmcnt(12)
    // At iter-i wait: outstanding st(i+1),x(i+1),st(i+2),x(i+2),st(i+3)=20;
    // retire 8 oldest = st(i+1)+x(i+1) -> next iter's inputs ready.
#pragma unroll
    for (int i = 0; i <= 28; ++i) {
        COMPUTE(i, i & 3, i & 1, sc4[i >> 3][(i >> 1) & 3]);
        XLOAD(i + 2, i & 1);
        asm volatile("" ::: "memory");
        STAGE(i + 3, (i + 3) & 3);
        asm volatile("s_waitcnt vmcnt(12)" ::: "memory");
        __builtin_amdgcn_sched_barrier(0);
    }
    // tail
    COMPUTE(29, 1, 1, sc4[3][2]);
    XLOAD(31, 1);
    asm volatile("s_waitcnt vmcnt(8)" ::: "memory");
    __builtin_amdgcn_sched_barrier(0);
    COMPUTE(30, 2, 0, sc4[3][3]);
    asm volatile("s_waitcnt vmcnt(0)" ::: "memory");
    __builtin_amdgcn_sched_barrier(0);
    COMPUTE(31, 3, 1, sc4[3][3]);

    // --- epilogue: single block-wide sync, pairwise wk-reduce, store ---
    __syncthreads();
    float* red = (float*)&lqw[0][0][0][0];    // [8][64][2][4] = 16 KB alias
#pragma unroll
    for (int h = 0; h < 2; ++h)
        *(f32x4*)&red[(size_t)(((wv * 64 + lane) * 2) + h) * 4] = acc[h];
    __syncthreads();
    if (wk == 0) {                             // even waves store
#pragma unroll
        for (int h = 0; h < 2; ++h) {
            f32x4 hi = *(const f32x4*)&red[(size_t)((((wv + 1) * 64 + lane) * 2) + h) * 4];
#pragma unroll
            for (int r = 0; r < 4; ++r)
                out[(size_t)(h * 16 + l4 * 4 + r) * OUT_F + col0 + l15] =
                    acc[h][r] + hi[r] + bv;
        }
    }
}

extern "C" void kernel_launch(void* const* d_in, const int* in_sizes, int n_in,
                              void* d_out, int out_size, void* d_ws, size_t ws_size,
                              hipStream_t stream) {
    const float* x      = (const float*)d_in[0];
    const int*   qw     = (const int*)d_in[1];
    const float* scales = (const float*)d_in[2];
    const float* bias   = (const float*)d_in[3];
    float*       out    = (float*)d_out;
    unsigned short* xT  = (unsigned short*)d_ws;   // 256 KB fragment-ordered x

    hipLaunchKernelGGL(xconv_kernel, dim3(64), dim3(256), 0, stream, x, xT);
    hipLaunchKernelGGL(qlin_kernel, dim3(OUT_F / 64), dim3(512), 0, stream,
                       xT, qw, scales, bias, out);
}